// Round 8
// baseline (319.183 us; speedup 1.0000x reference)
//
#include <hip/hip_runtime.h>
#include <math.h>

#define L_SEQ 2048
#define E_DIM 2048
#define H_NUM 16
#define D_HEAD 128

typedef __attribute__((ext_vector_type(8))) _Float16 half8;
typedef __attribute__((ext_vector_type(4))) _Float16 half4;
typedef __attribute__((ext_vector_type(4))) float floatx4;

// async global->LDS, 16B per lane. LDS dest is wave-uniform base + lane*16.
static __device__ __forceinline__ void gload16(const void* g, void* lds) {
  __builtin_amdgcn_global_load_lds(
      (const __attribute__((address_space(1))) void*)g,
      (__attribute__((address_space(3))) void*)lds, 16, 0, 0);
}

// ---------------------------------------------------------------------------
// MFMA GEMM (NT) v3: double-buffered LDS, ONE barrier per K-iter, with
// optional in-staging fp32->fp16 conversion (CVTA/CVTB): converted operands
// are loaded to regs as float4x2 at iter start (latency hidden by compute),
// converted + ds_write'd into buf[nxt] at iter end. Non-converted operands
// use async global_load_lds. EPI: 0 = fp32 C + bias; 1 = qkv split.
// ---------------------------------------------------------------------------
template <int TM, int TN, int WR, int WC, int EPI, int CVTA, int CVTB>
__global__ __launch_bounds__(256, 2)
void gemm_mfma(const void* __restrict__ Ap, const void* __restrict__ Bp,
               const float* __restrict__ bias, float* __restrict__ C,
               _Float16* __restrict__ qk, _Float16* __restrict__ vt,
               int M, int N, int K) {
  constexpr int RT = TM / (16 * WR);
  constexpr int CT = TN / (16 * WC);
  constexpr int ACH = TM / 8;           // 1KB chunks in A tile
  constexpr int NCH = (TM + TN) / 32;   // chunks staged per wave

  const _Float16* A16 = (const _Float16*)Ap;
  const float*    A32 = (const float*)Ap;
  const _Float16* B16 = (const _Float16*)Bp;
  const float*    B32 = (const float*)Bp;

  __shared__ _Float16 As[2][TM * 64];
  __shared__ _Float16 Bs[2][TN * 64];

  const int tid = threadIdx.x;
  const int wave = tid >> 6, lane = tid & 63;
  const int l15 = lane & 15, quad = lane >> 4;
  const int wr = wave / WC, wc = wave % WC;
  const int row0 = blockIdx.y * TM, col0 = blockIdx.x * TN;

  const int srow = lane >> 3;             // row within 8-row chunk
  const int gc = (lane & 7) ^ srow;       // swizzled source 16B(fp16) chunk

  float4 sreg[NCH][2];                    // staging regs for converted chunks

  // load converted chunks' fp32 into regs
  auto loadRegs = [&](int k0) {
#pragma unroll
    for (int c = 0; c < NCH; ++c) {
      int chunk = wave * NCH + c;
      if (chunk < ACH) {
        if (CVTA) {
          int row = chunk * 8 + srow;
          const float* p = A32 + (size_t)(row0 + row) * K + k0 + gc * 8;
          sreg[c][0] = *(const float4*)p;
          sreg[c][1] = *(const float4*)(p + 4);
        }
      } else {
        if (CVTB) {
          int row = (chunk - ACH) * 8 + srow;
          const float* p = B32 + (size_t)(col0 + row) * K + k0 + gc * 8;
          sreg[c][0] = *(const float4*)p;
          sreg[c][1] = *(const float4*)(p + 4);
        }
      }
    }
  };
  // async-DMA the non-converted chunks
  auto issueAsync = [&](int buf, int k0) {
#pragma unroll
    for (int c = 0; c < NCH; ++c) {
      int chunk = wave * NCH + c;
      if (chunk < ACH) {
        if (!CVTA) {
          int row = chunk * 8 + srow;
          gload16((const char*)(A16 + (size_t)(row0 + row) * K + k0) + gc * 16,
                  (char*)&As[buf][0] + chunk * 1024);
        }
      } else {
        if (!CVTB) {
          int row = (chunk - ACH) * 8 + srow;
          gload16((const char*)(B16 + (size_t)(col0 + row) * K + k0) + gc * 16,
                  (char*)&Bs[buf][0] + (chunk - ACH) * 1024);
        }
      }
    }
  };
  // convert + write converted chunks into buf
  auto writeRegs = [&](int buf) {
#pragma unroll
    for (int c = 0; c < NCH; ++c) {
      int chunk = wave * NCH + c;
      bool docvt = (chunk < ACH) ? (CVTA != 0) : (CVTB != 0);
      if (docvt) {
        float4 a = sreg[c][0], b = sreg[c][1];
        half8 h = {(_Float16)a.x, (_Float16)a.y, (_Float16)a.z, (_Float16)a.w,
                   (_Float16)b.x, (_Float16)b.y, (_Float16)b.z, (_Float16)b.w};
        char* base = (chunk < ACH)
                         ? (char*)&As[buf][0] + chunk * 1024
                         : (char*)&Bs[buf][0] + (chunk - ACH) * 1024;
        *(half8*)(base + lane * 16) = h;
      }
    }
  };

  floatx4 acc[RT][CT];
#pragma unroll
  for (int i = 0; i < RT; ++i)
#pragma unroll
    for (int j = 0; j < CT; ++j) acc[i][j] = (floatx4){0.f, 0.f, 0.f, 0.f};

  const int niter = K / 64;
  // prologue: tile 0 into buf0
  loadRegs(0);
  issueAsync(0, 0);
  writeRegs(0);

  for (int it = 0; it < niter; ++it) {
    const int cur = it & 1;
    __syncthreads();  // drains vmcnt: buf[cur] visible; buf[cur^1] readers done
    if (it + 1 < niter) {
      loadRegs((it + 1) * 64);
      issueAsync(cur ^ 1, (it + 1) * 64);
    }

#pragma unroll
    for (int ks = 0; ks < 2; ++ks) {
      half8 af[RT], bf[CT];
#pragma unroll
      for (int t = 0; t < RT; ++t) {
        int r = wr * (16 * RT) + t * 16 + l15;
        af[t] = *(const half8*)&As[cur][r * 64 + (((ks * 4 + quad) ^ (r & 7)) * 8)];
      }
#pragma unroll
      for (int t = 0; t < CT; ++t) {
        int r = wc * (16 * CT) + t * 16 + l15;
        bf[t] = *(const half8*)&Bs[cur][r * 64 + (((ks * 4 + quad) ^ (r & 7)) * 8)];
      }
#pragma unroll
      for (int tr = 0; tr < RT; ++tr)
#pragma unroll
        for (int tc = 0; tc < CT; ++tc)
          acc[tr][tc] = __builtin_amdgcn_mfma_f32_16x16x32_f16(
              af[tr], bf[tc], acc[tr][tc], 0, 0, 0);
    }

    if (it + 1 < niter) writeRegs(cur ^ 1);
  }

  const int crow = row0 + wr * (16 * RT);
  const int ccol = col0 + wc * (16 * CT);

  if (EPI == 0) {
#pragma unroll
    for (int tc = 0; tc < CT; ++tc) {
      int col = ccol + tc * 16 + l15;
      float bb = bias[col];
#pragma unroll
      for (int tr = 0; tr < RT; ++tr)
#pragma unroll
        for (int r = 0; r < 4; ++r)
          C[(size_t)(crow + tr * 16 + quad * 4 + r) * N + col] =
              acc[tr][tc][r] + bb;
    }
  } else if (col0 < 2 * E_DIM) {
#pragma unroll
    for (int tc = 0; tc < CT; ++tc) {
      int col = ccol + tc * 16 + l15;
      float bb = bias[col];
#pragma unroll
      for (int tr = 0; tr < RT; ++tr)
#pragma unroll
        for (int r = 0; r < 4; ++r)
          qk[(size_t)(crow + tr * 16 + quad * 4 + r) * (2 * E_DIM) + col] =
              (_Float16)(acc[tr][tc][r] + bb);
    }
  } else {
#pragma unroll
    for (int tc = 0; tc < CT; ++tc) {
      int col = ccol + tc * 16 + l15;
      float bb = bias[col];
      int vrow = col - 2 * E_DIM;
#pragma unroll
      for (int tr = 0; tr < RT; ++tr) {
        int rbase = crow + tr * 16 + quad * 4;
        half4 h = {(_Float16)(acc[tr][tc][0] + bb), (_Float16)(acc[tr][tc][1] + bb),
                   (_Float16)(acc[tr][tc][2] + bb), (_Float16)(acc[tr][tc][3] + bb)};
        *(half4*)&vt[(size_t)vrow * L_SEQ + rbase] = h;
      }
    }
  }
}

// ---------------------------------------------------------------------------
// MFMA flash attention v5. Grid (H, L/128) = 256 blocks, 512 thr = 8 waves
// -> 2 waves/SIMD (latency hiding; no extra HBM traffic vs v4).
// Wave owns 16 q-rows. Bc=64 keys/iter, 32 iters, double-buffered K/V LDS,
// one barrier/iter, reg-prefetch of next tile + bias, S^T=K*Q^T trick,
// no-max softmax (scores bounded ~|5.5|, exact at final divide).
// ---------------------------------------------------------------------------
__global__ __launch_bounds__(512, 2)
void attn_mfma(const _Float16* __restrict__ qk, const _Float16* __restrict__ vt,
               const float* __restrict__ bias, _Float16* __restrict__ ctx) {
  const int h = blockIdx.x;
  const int q0 = blockIdx.y * 128;
  const int tid = threadIdx.x;
  const int wave = tid >> 6;
  const int lane = tid & 63;
  const int l15 = lane & 15;
  const int quad = lane >> 4;

  __shared__ _Float16 Ks[2][64][136];   // [buf][key][d]
  __shared__ _Float16 Vst[2][128][72];  // [buf][d][key]
  __shared__ _Float16 Ps[128][72];      // [q][key] (same-wave use only)

  // Q fragments (B-operand: B[k=quad*8+j][n=l15=q]):
  half8 qa[4];
  {
    const _Float16* qp = qk + (size_t)(q0 + wave * 16 + l15) * (2 * E_DIM) +
                         h * D_HEAD + quad * 8;
#pragma unroll
    for (int ks = 0; ks < 4; ++ks) qa[ks] = *(const half8*)(qp + ks * 32);
  }

  float l_i = 0.f;
  floatx4 o[8];
#pragma unroll
  for (int t = 0; t < 8; ++t) o[t] = (floatx4){0.f, 0.f, 0.f, 0.f};

  const float scale = 0.088388347648318447f;  // 1/sqrt(128)

  // staging (512 threads, 2 chunks each of K and V):
  //   K: m=c*512+tid -> key=m>>4, d8=(m&15)*8 ; V: d=m>>3, ko=(m&7)*8
  half8 kreg[2], vreg[2];
  floatx4 bcur[4], bnxt[4];
#pragma unroll
  for (int c = 0; c < 2; ++c) {
    int m = c * 512 + tid;
    kreg[c] = *(const half8*)(qk + (size_t)(m >> 4) * (2 * E_DIM) + E_DIM +
                              h * D_HEAD + (m & 15) * 8);
    vreg[c] = *(const half8*)(vt + (size_t)(h * D_HEAD + (m >> 3)) * L_SEQ +
                              (m & 7) * 8);
  }
#pragma unroll
  for (int t = 0; t < 4; ++t)
    bcur[t] = *(const floatx4*)&bias[(size_t)(q0 + wave * 16 + l15) * L_SEQ +
                                    16 * t + quad * 4];
  // write buf 0 (fresh LDS, no barrier needed before)
#pragma unroll
  for (int c = 0; c < 2; ++c) {
    int m = c * 512 + tid;
    *(half8*)&Ks[0][m >> 4][(m & 15) * 8] = kreg[c];
    *(half8*)&Vst[0][m >> 3][(m & 7) * 8] = vreg[c];
  }

#pragma unroll 2
  for (int it = 0; it < 32; ++it) {
    const int cur = it & 1, nxt = cur ^ 1;
    const int kt = it * 64;
    __syncthreads();  // buf[cur] writes visible; buf[nxt] readers (it-1) done

    // ---- prefetch tile it+1 into regs (lands during this iter's compute) ----
    if (it < 31) {
#pragma unroll
      for (int c = 0; c < 2; ++c) {
        int m = c * 512 + tid;
        kreg[c] = *(const half8*)(qk + (size_t)(kt + 64 + (m >> 4)) * (2 * E_DIM) +
                                  E_DIM + h * D_HEAD + (m & 15) * 8);
        vreg[c] = *(const half8*)(vt + (size_t)(h * D_HEAD + (m >> 3)) * L_SEQ +
                                  kt + 64 + (m & 7) * 8);
      }
#pragma unroll
      for (int t = 0; t < 4; ++t)
        bnxt[t] = *(const floatx4*)&bias[(size_t)(q0 + wave * 16 + l15) * L_SEQ +
                                         kt + 64 + 16 * t + quad * 4];
    }

    // ---- S^T = K Q^T : col=l15=q, row=quad*4+reg=key(within 16t) ----
    floatx4 st[4];
#pragma unroll
    for (int t = 0; t < 4; ++t) st[t] = (floatx4){0.f, 0.f, 0.f, 0.f};
#pragma unroll
    for (int ks = 0; ks < 4; ++ks)
#pragma unroll
      for (int t = 0; t < 4; ++t) {
        half8 kf = *(const half8*)&Ks[cur][16 * t + l15][ks * 32 + quad * 8];
        st[t] = __builtin_amdgcn_mfma_f32_16x16x32_f16(kf, qa[ks], st[t], 0, 0, 0);
      }

    // ---- softmax (no max subtraction) + P^T pack -> Ps[q][key] ----
    {
      float ls = 0.f;
      float ps[4][4];
#pragma unroll
      for (int t = 0; t < 4; ++t)
#pragma unroll
        for (int r = 0; r < 4; ++r) {
          float p = __expf(fmaf(st[t][r], scale, bcur[t][r]));
          ps[t][r] = p;
          ls += p;
        }
      ls += __shfl_xor(ls, 16);
      ls += __shfl_xor(ls, 32);
      l_i += ls;
#pragma unroll
      for (int t = 0; t < 4; ++t) {
        half4 hp = {(_Float16)ps[t][0], (_Float16)ps[t][1],
                    (_Float16)ps[t][2], (_Float16)ps[t][3]};
        *(half4*)&Ps[wave * 16 + l15][16 * t + quad * 4] = hp;
      }
    }

    // ---- O += P V (A=P own rows; B=V^T; same-wave, no barrier) ----
    half8 pa[2];
#pragma unroll
    for (int ks = 0; ks < 2; ++ks)
      pa[ks] = *(const half8*)&Ps[wave * 16 + l15][ks * 32 + quad * 8];
#pragma unroll
    for (int t = 0; t < 8; ++t)
#pragma unroll
      for (int ks = 0; ks < 2; ++ks) {
        half8 vf = *(const half8*)&Vst[cur][16 * t + l15][ks * 32 + quad * 8];
        o[t] = __builtin_amdgcn_mfma_f32_16x16x32_f16(pa[ks], vf, o[t], 0, 0, 0);
      }

    // ---- stage tile it+1 into buf[nxt]; rotate bias regs ----
    if (it < 31) {
#pragma unroll
      for (int c = 0; c < 2; ++c) {
        int m = c * 512 + tid;
        *(half8*)&Ks[nxt][m >> 4][(m & 15) * 8] = kreg[c];
        *(half8*)&Vst[nxt][m >> 3][(m & 7) * 8] = vreg[c];
      }
#pragma unroll
      for (int t = 0; t < 4; ++t) bcur[t] = bnxt[t];
    }
  }

  // ---- epilogue: ctx = O / l. l lives at lane l15=q; o rows are quad*4+r ----
  float inv[4];
#pragma unroll
  for (int r = 0; r < 4; ++r) inv[r] = 1.f / __shfl(l_i, quad * 4 + r);
#pragma unroll
  for (int t = 0; t < 8; ++t)
#pragma unroll
    for (int r = 0; r < 4; ++r) {
      int row = q0 + wave * 16 + quad * 4 + r;
      ctx[(size_t)row * E_DIM + h * D_HEAD + 16 * t + l15] =
          (_Float16)(o[t][r] * inv[r]);
    }
}

// ---------------------------------------------------------------------------
extern "C" void kernel_launch(void* const* d_in, const int* in_sizes, int n_in,
                              void* d_out, int out_size, void* d_ws, size_t ws_size,
                              hipStream_t stream) {
  const float* x          = (const float*)d_in[0];
  const float* bias_mat   = (const float*)d_in[1];
  const float* in_proj_w  = (const float*)d_in[2];
  const float* in_proj_b  = (const float*)d_in[3];
  const float* out_proj_w = (const float*)d_in[4];
  const float* out_proj_b = (const float*)d_in[5];
  float* out = (float*)d_out;

  // ws layout (halfs): qk [L][2E] | vt [E][L] | ctx [L][E]
  _Float16* qk  = (_Float16*)d_ws;
  _Float16* vt  = qk + (size_t)L_SEQ * 2 * E_DIM;
  _Float16* ctx = vt + (size_t)E_DIM * L_SEQ;

  // 1) qkv projection from fp32 x/w1 (in-staging conversion); splits qk + vt
  gemm_mfma<128, 128, 2, 2, 1, 1, 1>
      <<<dim3(3 * E_DIM / 128, L_SEQ / 128), dim3(256), 0, stream>>>(
          x, in_proj_w, in_proj_b, nullptr, qk, vt, L_SEQ, 3 * E_DIM, E_DIM);

  // 2) flash attention -> ctx fp16
  attn_mfma<<<dim3(H_NUM, L_SEQ / 128), dim3(512), 0, stream>>>(qk, vt, bias_mat,
                                                                ctx);

  // 3) out projection: A=ctx fp16 (async DMA), B=w2 fp32 (in-staging cvt)
  gemm_mfma<128, 64, 4, 1, 0, 0, 1>
      <<<dim3(E_DIM / 64, L_SEQ / 128), dim3(256), 0, stream>>>(
          ctx, out_proj_w, out_proj_b, out, nullptr, nullptr, L_SEQ, E_DIM, E_DIM);
}

// Round 9
// 284.406 us; speedup vs baseline: 1.1223x; 1.1223x over previous
//
#include <hip/hip_runtime.h>
#include <math.h>

#define L_SEQ 2048
#define E_DIM 2048
#define H_NUM 16
#define D_HEAD 128

typedef __attribute__((ext_vector_type(8))) _Float16 half8;
typedef __attribute__((ext_vector_type(4))) _Float16 half4;
typedef __attribute__((ext_vector_type(4))) float floatx4;

// async global->LDS, 16B per lane. LDS dest is wave-uniform base + lane*16.
static __device__ __forceinline__ void gload16(const void* g, void* lds) {
  __builtin_amdgcn_global_load_lds(
      (const __attribute__((address_space(1))) void*)g,
      (__attribute__((address_space(3))) void*)lds, 16, 0, 0);
}

// ---------------------------------------------------------------------------
// Fused fp32 -> fp16 conversion of x, in_proj_w, out_proj_w (one launch).
// One-time pass: reading fp32 inside the GEMMs costs 2.3x HBM (R8 lesson).
// ---------------------------------------------------------------------------
__global__ __launch_bounds__(256)
void cvt3_f32_f16(const float* __restrict__ a, _Float16* __restrict__ oa, int na,
                  const float* __restrict__ b, _Float16* __restrict__ ob, int nb,
                  const float* __restrict__ c, _Float16* __restrict__ oc, int nc) {
  int i = (blockIdx.x * 256 + threadIdx.x) * 8;
  const float* src;
  _Float16* dst;
  if (i < na) {
    src = a + i; dst = oa + i;
  } else if (i < na + nb) {
    src = b + (i - na); dst = ob + (i - na);
  } else if (i < na + nb + nc) {
    src = c + (i - na - nb); dst = oc + (i - na - nb);
  } else {
    return;
  }
  float4 p = *(const float4*)src;
  float4 q = *(const float4*)(src + 4);
  half8 h = {(_Float16)p.x, (_Float16)p.y, (_Float16)p.z, (_Float16)p.w,
             (_Float16)q.x, (_Float16)q.y, (_Float16)q.z, (_Float16)q.w};
  *(half8*)dst = h;
}

// ---------------------------------------------------------------------------
// MFMA GEMM (NT) v2 (R7-verified): double-buffered LDS, ONE barrier per
// K-iter, async global_load_lds staging, fp16 in, fp32 acc. BK=64.
// EPI: 0 = fp32 C + bias (out-proj); 1 = qkv split (fp16 qk rows / vt^T).
// ---------------------------------------------------------------------------
template <int TM, int TN, int WR, int WC, int EPI>
__global__ __launch_bounds__(256)
void gemm_mfma(const _Float16* __restrict__ A, const _Float16* __restrict__ B,
               const float* __restrict__ bias, float* __restrict__ C,
               _Float16* __restrict__ qk, _Float16* __restrict__ vt,
               int M, int N, int K) {
  constexpr int RT = TM / (16 * WR);
  constexpr int CT = TN / (16 * WC);
  constexpr int ACH = TM / 8;
  constexpr int NCH = (TM + TN) / 32;

  __shared__ _Float16 As[2][TM * 64];
  __shared__ _Float16 Bs[2][TN * 64];

  const int tid = threadIdx.x;
  const int wave = tid >> 6, lane = tid & 63;
  const int l15 = lane & 15, quad = lane >> 4;
  const int wr = wave / WC, wc = wave % WC;
  const int row0 = blockIdx.y * TM, col0 = blockIdx.x * TN;

  const int srow = lane >> 3;
  const int gc = (lane & 7) ^ srow;

  auto stage = [&](int buf, int k0) {
#pragma unroll
    for (int c = 0; c < NCH; ++c) {
      int chunk = wave * NCH + c;
      if (chunk < ACH) {
        int row = chunk * 8 + srow;
        gload16((const char*)(A + (size_t)(row0 + row) * K + k0) + gc * 16,
                (char*)&As[buf][0] + chunk * 1024);
      } else {
        int bch = chunk - ACH;
        int row = bch * 8 + srow;
        gload16((const char*)(B + (size_t)(col0 + row) * K + k0) + gc * 16,
                (char*)&Bs[buf][0] + bch * 1024);
      }
    }
  };

  floatx4 acc[RT][CT];
#pragma unroll
  for (int i = 0; i < RT; ++i)
#pragma unroll
    for (int j = 0; j < CT; ++j) acc[i][j] = (floatx4){0.f, 0.f, 0.f, 0.f};

  const int niter = K / 64;
  stage(0, 0);

  for (int it = 0; it < niter; ++it) {
    const int cur = it & 1;
    __syncthreads();  // buf[cur] loads landed during previous compute
    if (it + 1 < niter) stage(cur ^ 1, (it + 1) * 64);

#pragma unroll
    for (int ks = 0; ks < 2; ++ks) {
      half8 af[RT], bf[CT];
#pragma unroll
      for (int t = 0; t < RT; ++t) {
        int r = wr * (16 * RT) + t * 16 + l15;
        af[t] = *(const half8*)&As[cur][r * 64 + (((ks * 4 + quad) ^ (r & 7)) * 8)];
      }
#pragma unroll
      for (int t = 0; t < CT; ++t) {
        int r = wc * (16 * CT) + t * 16 + l15;
        bf[t] = *(const half8*)&Bs[cur][r * 64 + (((ks * 4 + quad) ^ (r & 7)) * 8)];
      }
#pragma unroll
      for (int tr = 0; tr < RT; ++tr)
#pragma unroll
        for (int tc = 0; tc < CT; ++tc)
          acc[tr][tc] = __builtin_amdgcn_mfma_f32_16x16x32_f16(
              af[tr], bf[tc], acc[tr][tc], 0, 0, 0);
    }
  }

  const int crow = row0 + wr * (16 * RT);
  const int ccol = col0 + wc * (16 * CT);

  if (EPI == 0) {
#pragma unroll
    for (int tc = 0; tc < CT; ++tc) {
      int col = ccol + tc * 16 + l15;
      float bb = bias[col];
#pragma unroll
      for (int tr = 0; tr < RT; ++tr)
#pragma unroll
        for (int r = 0; r < 4; ++r)
          C[(size_t)(crow + tr * 16 + quad * 4 + r) * N + col] =
              acc[tr][tc][r] + bb;
    }
  } else if (col0 < 2 * E_DIM) {
#pragma unroll
    for (int tc = 0; tc < CT; ++tc) {
      int col = ccol + tc * 16 + l15;
      float bb = bias[col];
#pragma unroll
      for (int tr = 0; tr < RT; ++tr)
#pragma unroll
        for (int r = 0; r < 4; ++r)
          qk[(size_t)(crow + tr * 16 + quad * 4 + r) * (2 * E_DIM) + col] =
              (_Float16)(acc[tr][tc][r] + bb);
    }
  } else {
#pragma unroll
    for (int tc = 0; tc < CT; ++tc) {
      int col = ccol + tc * 16 + l15;
      float bb = bias[col];
      int vrow = col - 2 * E_DIM;
#pragma unroll
      for (int tr = 0; tr < RT; ++tr) {
        int rbase = crow + tr * 16 + quad * 4;
        half4 h = {(_Float16)(acc[tr][tc][0] + bb), (_Float16)(acc[tr][tc][1] + bb),
                   (_Float16)(acc[tr][tc][2] + bb), (_Float16)(acc[tr][tc][3] + bb)};
        *(half4*)&vt[(size_t)vrow * L_SEQ + rbase] = h;
      }
    }
  }
}

// ---------------------------------------------------------------------------
// MFMA flash attention v5. Grid (H, L/128) = 256 blocks, 512 thr = 8 waves
// -> 2 waves/SIMD (latency hiding; zero extra HBM traffic vs v4 — R5 lesson).
// Wave owns 16 q-rows. Bc=64 keys/iter, 32 iters, double-buffered K/V LDS,
// one barrier/iter, reg-prefetch of next tile + bias, S^T=K*Q^T trick,
// no-max softmax (scores bounded ~|5.5|, exact at final divide).
// ---------------------------------------------------------------------------
__global__ __launch_bounds__(512, 2)
void attn_mfma(const _Float16* __restrict__ qk, const _Float16* __restrict__ vt,
               const float* __restrict__ bias, _Float16* __restrict__ ctx) {
  const int h = blockIdx.x;
  const int q0 = blockIdx.y * 128;
  const int tid = threadIdx.x;
  const int wave = tid >> 6;
  const int lane = tid & 63;
  const int l15 = lane & 15;
  const int quad = lane >> 4;

  __shared__ _Float16 Ks[2][64][136];   // [buf][key][d]
  __shared__ _Float16 Vst[2][128][72];  // [buf][d][key]
  __shared__ _Float16 Ps[128][72];      // [q][key] (same-wave use only)

  // Q fragments (B-operand: B[k=quad*8+j][n=l15=q]):
  half8 qa[4];
  {
    const _Float16* qp = qk + (size_t)(q0 + wave * 16 + l15) * (2 * E_DIM) +
                         h * D_HEAD + quad * 8;
#pragma unroll
    for (int ks = 0; ks < 4; ++ks) qa[ks] = *(const half8*)(qp + ks * 32);
  }

  float l_i = 0.f;
  floatx4 o[8];
#pragma unroll
  for (int t = 0; t < 8; ++t) o[t] = (floatx4){0.f, 0.f, 0.f, 0.f};

  const float scale = 0.088388347648318447f;  // 1/sqrt(128)

  // staging (512 threads, 2 chunks each of K and V):
  half8 kreg[2], vreg[2];
  floatx4 bcur[4], bnxt[4];
#pragma unroll
  for (int c = 0; c < 2; ++c) {
    int m = c * 512 + tid;
    kreg[c] = *(const half8*)(qk + (size_t)(m >> 4) * (2 * E_DIM) + E_DIM +
                              h * D_HEAD + (m & 15) * 8);
    vreg[c] = *(const half8*)(vt + (size_t)(h * D_HEAD + (m >> 3)) * L_SEQ +
                              (m & 7) * 8);
  }
#pragma unroll
  for (int t = 0; t < 4; ++t)
    bcur[t] = *(const floatx4*)&bias[(size_t)(q0 + wave * 16 + l15) * L_SEQ +
                                    16 * t + quad * 4];
#pragma unroll
  for (int c = 0; c < 2; ++c) {
    int m = c * 512 + tid;
    *(half8*)&Ks[0][m >> 4][(m & 15) * 8] = kreg[c];
    *(half8*)&Vst[0][m >> 3][(m & 7) * 8] = vreg[c];
  }

#pragma unroll 2
  for (int it = 0; it < 32; ++it) {
    const int cur = it & 1, nxt = cur ^ 1;
    const int kt = it * 64;
    __syncthreads();  // buf[cur] writes visible; buf[nxt] readers (it-1) done

    if (it < 31) {
#pragma unroll
      for (int c = 0; c < 2; ++c) {
        int m = c * 512 + tid;
        kreg[c] = *(const half8*)(qk + (size_t)(kt + 64 + (m >> 4)) * (2 * E_DIM) +
                                  E_DIM + h * D_HEAD + (m & 15) * 8);
        vreg[c] = *(const half8*)(vt + (size_t)(h * D_HEAD + (m >> 3)) * L_SEQ +
                                  kt + 64 + (m & 7) * 8);
      }
#pragma unroll
      for (int t = 0; t < 4; ++t)
        bnxt[t] = *(const floatx4*)&bias[(size_t)(q0 + wave * 16 + l15) * L_SEQ +
                                         kt + 64 + 16 * t + quad * 4];
    }

    // ---- S^T = K Q^T : col=l15=q, row=quad*4+reg=key(within 16t) ----
    floatx4 st[4];
#pragma unroll
    for (int t = 0; t < 4; ++t) st[t] = (floatx4){0.f, 0.f, 0.f, 0.f};
#pragma unroll
    for (int ks = 0; ks < 4; ++ks)
#pragma unroll
      for (int t = 0; t < 4; ++t) {
        half8 kf = *(const half8*)&Ks[cur][16 * t + l15][ks * 32 + quad * 8];
        st[t] = __builtin_amdgcn_mfma_f32_16x16x32_f16(kf, qa[ks], st[t], 0, 0, 0);
      }

    // ---- softmax (no max subtraction) + P^T pack -> Ps[q][key] ----
    {
      float ls = 0.f;
      float ps[4][4];
#pragma unroll
      for (int t = 0; t < 4; ++t)
#pragma unroll
        for (int r = 0; r < 4; ++r) {
          float p = __expf(fmaf(st[t][r], scale, bcur[t][r]));
          ps[t][r] = p;
          ls += p;
        }
      ls += __shfl_xor(ls, 16);
      ls += __shfl_xor(ls, 32);
      l_i += ls;
#pragma unroll
      for (int t = 0; t < 4; ++t) {
        half4 hp = {(_Float16)ps[t][0], (_Float16)ps[t][1],
                    (_Float16)ps[t][2], (_Float16)ps[t][3]};
        *(half4*)&Ps[wave * 16 + l15][16 * t + quad * 4] = hp;
      }
    }

    // ---- O += P V (A=P own rows; B=V^T; same-wave, no barrier) ----
    half8 pa[2];
#pragma unroll
    for (int ks = 0; ks < 2; ++ks)
      pa[ks] = *(const half8*)&Ps[wave * 16 + l15][ks * 32 + quad * 8];
#pragma unroll
    for (int t = 0; t < 8; ++t)
#pragma unroll
      for (int ks = 0; ks < 2; ++ks) {
        half8 vf = *(const half8*)&Vst[cur][16 * t + l15][ks * 32 + quad * 8];
        o[t] = __builtin_amdgcn_mfma_f32_16x16x32_f16(pa[ks], vf, o[t], 0, 0, 0);
      }

    if (it < 31) {
#pragma unroll
      for (int c = 0; c < 2; ++c) {
        int m = c * 512 + tid;
        *(half8*)&Ks[nxt][m >> 4][(m & 15) * 8] = kreg[c];
        *(half8*)&Vst[nxt][m >> 3][(m & 7) * 8] = vreg[c];
      }
#pragma unroll
      for (int t = 0; t < 4; ++t) bcur[t] = bnxt[t];
    }
  }

  // ---- epilogue: ctx = O / l. l lives at lane l15=q; o rows are quad*4+r ----
  float inv[4];
#pragma unroll
  for (int r = 0; r < 4; ++r) inv[r] = 1.f / __shfl(l_i, quad * 4 + r);
#pragma unroll
  for (int t = 0; t < 8; ++t)
#pragma unroll
    for (int r = 0; r < 4; ++r) {
      int row = q0 + wave * 16 + quad * 4 + r;
      ctx[(size_t)row * E_DIM + h * D_HEAD + 16 * t + l15] =
          (_Float16)(o[t][r] * inv[r]);
    }
}

// ---------------------------------------------------------------------------
extern "C" void kernel_launch(void* const* d_in, const int* in_sizes, int n_in,
                              void* d_out, int out_size, void* d_ws, size_t ws_size,
                              hipStream_t stream) {
  const float* x          = (const float*)d_in[0];
  const float* bias_mat   = (const float*)d_in[1];
  const float* in_proj_w  = (const float*)d_in[2];
  const float* in_proj_b  = (const float*)d_in[3];
  const float* out_proj_w = (const float*)d_in[4];
  const float* out_proj_b = (const float*)d_in[5];
  float* out = (float*)d_out;

  _Float16* x16 = (_Float16*)d_ws;                         // L*E
  _Float16* w1  = x16 + (size_t)L_SEQ * E_DIM;             // 3E*E
  _Float16* w2  = w1 + (size_t)3 * E_DIM * E_DIM;          // E*E
  _Float16* qk  = w2 + (size_t)E_DIM * E_DIM;              // L*2E
  _Float16* vt  = qk + (size_t)L_SEQ * 2 * E_DIM;          // E*L
  _Float16* ctx = vt + (size_t)E_DIM * L_SEQ;              // L*E

  dim3 blk(256);
  const int nx = L_SEQ * E_DIM, nw1 = 3 * E_DIM * E_DIM, nw2 = E_DIM * E_DIM;

  cvt3_f32_f16<<<(nx + nw1 + nw2) / 2048, blk, 0, stream>>>(
      x, x16, nx, in_proj_w, w1, nw1, out_proj_w, w2, nw2);

  gemm_mfma<128, 128, 2, 2, 1><<<dim3(3 * E_DIM / 128, L_SEQ / 128), blk, 0, stream>>>(
      x16, w1, in_proj_b, nullptr, qk, vt, L_SEQ, 3 * E_DIM, E_DIM);

  attn_mfma<<<dim3(H_NUM, L_SEQ / 128), dim3(512), 0, stream>>>(qk, vt, bias_mat,
                                                                ctx);

  gemm_mfma<128, 64, 4, 1, 0><<<dim3(E_DIM / 64, L_SEQ / 128), blk, 0, stream>>>(
      ctx, w2, out_proj_b, out, nullptr, nullptr, L_SEQ, E_DIM, E_DIM);
}